// Round 1
// baseline (25923.425 us; speedup 1.0000x reference)
//
#include <hip/hip_runtime.h>
#include <stdint.h>

// Furthest Point Sampling, B=8, N=131072, NPOINT=2048, exact-match vs JAX ref.
// Strategy: 256 persistent blocks (32 per batch, batch = blockIdx%8 so one
// batch maps to one XCD). Points + running min-dists live in registers.
// Per round: local argmax -> release-store packed partial -> batch-leader
// block polls 32 partials (lane-parallel), reduces, broadcasts winner idx.

#define NB 8
#define NPTS 131072
#define NPOINT 2048
#define KBLK 32                 // blocks per batch
#define BLOCK 512
#define PPT 8                   // NPTS / (KBLK*BLOCK)
#define NWAVES (BLOCK / 64)
#define PSTRIDE 8               // uint64 stride -> 64B padding

__device__ uint64_t g_part[NB][KBLK * PSTRIDE];
__device__ uint64_t g_bcast[NB * PSTRIDE];

static __device__ __forceinline__ uint64_t ld_acq(uint64_t* p) {
  return __hip_atomic_load(p, __ATOMIC_ACQUIRE, __HIP_MEMORY_SCOPE_AGENT);
}
static __device__ __forceinline__ void st_rel(uint64_t* p, uint64_t v) {
  __hip_atomic_store(p, v, __ATOMIC_RELEASE, __HIP_MEMORY_SCOPE_AGENT);
}

__global__ __launch_bounds__(BLOCK, 1) void fps_kernel(
    const float* __restrict__ xyz, int* __restrict__ out) {
  const int b = blockIdx.x & (NB - 1);   // batch -> same XCD for all its blocks
  const int k = blockIdx.x >> 3;         // block-within-batch
  const int tid = threadIdx.x;
  const int lane = tid & 63;
  const int wid = tid >> 6;

  const float* __restrict__ X = xyz + (size_t)b * 3u * NPTS;
  const float* __restrict__ Y = X + NPTS;
  const float* __restrict__ Z = Y + NPTS;

  const int base = k * (BLOCK * PPT);

  // Resident state: points and min-dists in registers for the whole kernel.
  float px[PPT], py[PPT], pz[PPT], dist[PPT];
#pragma unroll
  for (int j = 0; j < PPT; ++j) {
    int i = base + j * BLOCK + tid;
    px[j] = X[i];
    py[j] = Y[i];
    pz[j] = Z[i];
    dist[j] = 1e10f;
  }

  __shared__ uint64_t sh_w[NWAVES];
  __shared__ int sh_idx;

  if (k == 0 && tid == 0) out[b * NPOINT] = 0;  // first sampled index is 0

  int cur = 0;

  for (int r = 1; r < NPOINT; ++r) {
    // coords of last selected point (uniform; same-address load broadcasts)
    const int lu = __builtin_amdgcn_readfirstlane(cur);
    const float qx = X[lu];
    const float qy = Y[lu];
    const float qz = Z[lu];

    // update dists, local packed argmax (max value, min index on ties)
    uint64_t pm = 0;
#pragma unroll
    for (int j = 0; j < PPT; ++j) {
      float dx = __fsub_rn(px[j], qx);
      float dy = __fsub_rn(py[j], qy);
      float dz = __fsub_rn(pz[j], qz);
      // exact JAX order: (dx*dx + dy*dy) + dz*dz, no fma contraction
      float d = __fadd_rn(__fadd_rn(__fmul_rn(dx, dx), __fmul_rn(dy, dy)),
                          __fmul_rn(dz, dz));
      float nd = fminf(dist[j], d);
      dist[j] = nd;
      uint32_t idx = (uint32_t)(base + j * BLOCK + tid);
      uint64_t cand =
          ((uint64_t)__float_as_uint(nd) << 32) | (uint64_t)(0xFFFFFFFFu - idx);
      pm = cand > pm ? cand : pm;
    }

    // wave reduce (64 lanes)
#pragma unroll
    for (int off = 32; off; off >>= 1) {
      uint64_t o = (uint64_t)__shfl_xor((unsigned long long)pm, off, 64);
      pm = o > pm ? o : pm;
    }
    if (lane == 0) sh_w[wid] = pm;
    __syncthreads();

    // block reduce + publish partial: [fbits:32][idx:17 @bit12][tag:12]
    if (tid == 0) {
      uint64_t bm = sh_w[0];
#pragma unroll
      for (int wv = 1; wv < NWAVES; ++wv) {
        uint64_t o = sh_w[wv];
        bm = o > bm ? o : bm;
      }
      uint32_t fb = (uint32_t)(bm >> 32);
      uint32_t idx = 0xFFFFFFFFu - (uint32_t)bm;
      uint64_t w0 =
          ((uint64_t)fb << 32) | ((uint64_t)idx << 12) | (uint64_t)(uint32_t)r;
      st_rel(&g_part[b][k * PSTRIDE], w0);
    }

    if (k == 0) {
      // batch leader: wave 0 polls all 32 partials (one per lane), reduces
      if (tid < 64) {
        uint64_t pmr = 0;
        if (lane < KBLK) {
          uint64_t* pp = &g_part[b][lane * PSTRIDE];
          uint64_t w;
          do {
            w = ld_acq(pp);
          } while ((w & 0xFFFull) != (uint64_t)(uint32_t)r);
          uint32_t fb = (uint32_t)(w >> 32);
          uint32_t idx = (uint32_t)((w >> 12) & 0x1FFFFu);
          pmr = ((uint64_t)fb << 32) | (uint64_t)(0xFFFFFFFFu - idx);
        }
#pragma unroll
        for (int off = 16; off; off >>= 1) {
          uint64_t o = (uint64_t)__shfl_xor((unsigned long long)pmr, off, 64);
          pmr = o > pmr ? o : pmr;
        }
        if (tid == 0) {
          uint32_t widx = 0xFFFFFFFFu - (uint32_t)pmr;
          out[b * NPOINT + r] = (int)widx;
          st_rel(&g_bcast[b * PSTRIDE],
                 ((uint64_t)widx << 12) | (uint64_t)(uint32_t)r);
          sh_idx = (int)widx;
        }
      }
    } else {
      if (tid == 0) {
        uint64_t w;
        do {
          w = ld_acq(&g_bcast[b * PSTRIDE]);
        } while ((w & 0xFFFull) != (uint64_t)(uint32_t)r);
        sh_idx = (int)((w >> 12) & 0x1FFFFu);
      }
    }
    __syncthreads();
    cur = sh_idx;
  }
}

extern "C" void kernel_launch(void* const* d_in, const int* in_sizes, int n_in,
                              void* d_out, int out_size, void* d_ws,
                              size_t ws_size, hipStream_t stream) {
  (void)in_sizes; (void)n_in; (void)d_ws; (void)ws_size; (void)out_size;
  const float* xyz = (const float*)d_in[0];
  int* out = (int*)d_out;
  fps_kernel<<<dim3(NB * KBLK), dim3(BLOCK), 0, stream>>>(xyz, out);
}

// Round 2
// 4581.207 us; speedup vs baseline: 5.6586x; 5.6586x over previous
//
#include <hip/hip_runtime.h>
#include <stdint.h>

// Furthest Point Sampling, B=8, N=131072, NPOINT=2048, exact-match vs JAX ref.
// R2: single-hop sync. Every block publishes its per-round partial argmax as
// ONE relaxed 64-bit atomic word [fbits:32 | (131071-idx):17 @bit12 | tag:12];
// all 32 blocks of a batch poll all 32 slots (lane-parallel) and reduce
// locally. No acquire/release -> no waitcnt drains / cache-maintenance ops.

#define NB 8
#define NPTS 131072
#define NPOINT 2048
#define KBLK 32                 // blocks per batch
#define BLOCK 512
#define PPT 8                   // NPTS / (KBLK*BLOCK)
#define NWAVES (BLOCK / 64)
#define PSTRIDE 8               // uint64 stride -> 64B per slot (own cacheline)

__device__ uint64_t g_part[NB][KBLK * PSTRIDE];

static __device__ __forceinline__ uint64_t ld_rlx(uint64_t* p) {
  return __hip_atomic_load(p, __ATOMIC_RELAXED, __HIP_MEMORY_SCOPE_AGENT);
}
static __device__ __forceinline__ void st_rlx(uint64_t* p, uint64_t v) {
  __hip_atomic_store(p, v, __ATOMIC_RELAXED, __HIP_MEMORY_SCOPE_AGENT);
}

__global__ __launch_bounds__(BLOCK, 1) void fps_kernel(
    const float* __restrict__ xyz, int* __restrict__ out) {
  const int b = blockIdx.x & (NB - 1);   // batch -> same XCD for all its blocks
  const int k = blockIdx.x >> 3;         // block-within-batch
  const int tid = threadIdx.x;
  const int lane = tid & 63;
  const int wid = tid >> 6;

  const float* __restrict__ X = xyz + (size_t)b * 3u * NPTS;
  const float* __restrict__ Y = X + NPTS;
  const float* __restrict__ Z = Y + NPTS;

  const int base = k * (BLOCK * PPT);

  // Resident state: points and min-dists in registers for the whole kernel.
  float px[PPT], py[PPT], pz[PPT], dist[PPT];
#pragma unroll
  for (int j = 0; j < PPT; ++j) {
    int i = base + j * BLOCK + tid;
    px[j] = X[i];
    py[j] = Y[i];
    pz[j] = Z[i];
    dist[j] = 1e10f;
  }

  __shared__ uint64_t sh_w[NWAVES];
  __shared__ int sh_idx;

  if (k == 0 && tid == 0) out[b * NPOINT] = 0;  // first sampled index is 0

  int cur = 0;

  for (int r = 1; r < NPOINT; ++r) {
    // coords of last selected point (uniform; same-address load broadcasts)
    const int lu = __builtin_amdgcn_readfirstlane(cur);
    const float qx = X[lu];
    const float qy = Y[lu];
    const float qz = Z[lu];

    // update dists, local packed argmax. pack: [fbits:32 | (N-1-idx):17 @12]
    // (tag bits 0..11 left zero here; OR'd in at publish). Equal-tag words
    // compare correctly as raw uint64; ties -> smaller idx wins (JAX argmax).
    uint64_t pm = 0;
#pragma unroll
    for (int j = 0; j < PPT; ++j) {
      float dx = __fsub_rn(px[j], qx);
      float dy = __fsub_rn(py[j], qy);
      float dz = __fsub_rn(pz[j], qz);
      // exact JAX order: (dx*dx + dy*dy) + dz*dz, no fma contraction
      float d = __fadd_rn(__fadd_rn(__fmul_rn(dx, dx), __fmul_rn(dy, dy)),
                          __fmul_rn(dz, dz));
      float nd = fminf(dist[j], d);
      dist[j] = nd;
      uint32_t idx = (uint32_t)(base + j * BLOCK + tid);
      uint64_t cand = ((uint64_t)__float_as_uint(nd) << 32) |
                      ((uint64_t)(NPTS - 1u - idx) << 12);
      pm = cand > pm ? cand : pm;
    }

    // wave reduce (64 lanes)
#pragma unroll
    for (int off = 32; off; off >>= 1) {
      uint64_t o = (uint64_t)__shfl_xor((unsigned long long)pm, off, 64);
      pm = o > pm ? o : pm;
    }
    if (lane == 0) sh_w[wid] = pm;
    __syncthreads();

    // wave 0: block-reduce, publish, poll all 32 partials, reduce, broadcast
    if (tid < 64) {
      uint64_t bm = (lane < NWAVES) ? sh_w[lane] : 0;
#pragma unroll
      for (int off = 4; off; off >>= 1) {
        uint64_t o = (uint64_t)__shfl_xor((unsigned long long)bm, off, 64);
        bm = o > bm ? o : bm;
      }
      if (tid == 0) st_rlx(&g_part[b][k * PSTRIDE], bm | (uint64_t)(uint32_t)r);

      uint64_t w = 0;
      if (lane < KBLK) {
        uint64_t* pp = &g_part[b][lane * PSTRIDE];
        do {
          w = ld_rlx(pp);
        } while ((w & 0xFFFull) != (uint64_t)(uint32_t)r);
      }
#pragma unroll
      for (int off = 16; off; off >>= 1) {
        uint64_t o = (uint64_t)__shfl_xor((unsigned long long)w, off, 64);
        w = o > w ? o : w;
      }
      if (tid == 0) {
        int widx = (int)(NPTS - 1u - (uint32_t)((w >> 12) & 0x1FFFFu));
        if (k == 0) out[b * NPOINT + r] = widx;
        sh_idx = widx;
      }
    }
    __syncthreads();
    cur = sh_idx;
  }
}

extern "C" void kernel_launch(void* const* d_in, const int* in_sizes, int n_in,
                              void* d_out, int out_size, void* d_ws,
                              size_t ws_size, hipStream_t stream) {
  (void)in_sizes; (void)n_in; (void)d_ws; (void)ws_size; (void)out_size;
  const float* xyz = (const float*)d_in[0];
  int* out = (int*)d_out;
  fps_kernel<<<dim3(NB * KBLK), dim3(BLOCK), 0, stream>>>(xyz, out);
}